// Round 1
// baseline (954.196 us; speedup 1.0000x reference)
//
#include <hip/hip_runtime.h>
#include <math.h>

// Pass 1: global max(|x|) reduction (with the 1e-10 magnitude floor).
// float4 grid-stride loads -> wave shuffle reduce -> LDS -> one atomicMax
// per block on the float's bit pattern (all values positive => uint order
// == float order).
__global__ __launch_bounds__(256) void bq_max_kernel(
    const float4* __restrict__ x, unsigned int* __restrict__ max_bits,
    long long n4, const float* __restrict__ x_scalar, long long n) {
    float m = 0.0f;
    long long stride = (long long)gridDim.x * blockDim.x;
    for (long long i = (long long)blockIdx.x * blockDim.x + threadIdx.x;
         i < n4; i += stride) {
        float4 v = x[i];
        m = fmaxf(m, fmaxf(fmaxf(fabsf(v.x), fabsf(v.y)),
                           fmaxf(fabsf(v.z), fabsf(v.w))));
    }
    // scalar tail (n not multiple of 4) — handled by block 0 thread 0
    if (blockIdx.x == 0 && threadIdx.x == 0) {
        for (long long i = n4 * 4; i < n; ++i) m = fmaxf(m, fabsf(x_scalar[i]));
    }
    // wave-64 reduce
    #pragma unroll
    for (int off = 32; off > 0; off >>= 1)
        m = fmaxf(m, __shfl_down(m, off, 64));
    __shared__ float smem[4];
    int lane = threadIdx.x & 63;
    int wave = threadIdx.x >> 6;
    if (lane == 0) smem[wave] = m;
    __syncthreads();
    if (threadIdx.x == 0) {
        float bm = fmaxf(fmaxf(smem[0], smem[1]), fmaxf(smem[2], smem[3]));
        bm = fmaxf(bm, 1e-10f);  // magnitude floor (zeros -> 1e-10)
        atomicMax(max_bits, __float_as_uint(bm));
    }
}

__device__ __forceinline__ float bq_one(float x, float s, float inv) {
    // data = where(x >= 0, max(x, 1e-10), min(x, -1e-10));  -0.0 >= 0 is true
    float d = (x >= 0.0f) ? fmaxf(x, 1e-10f) : fminf(x, -1e-10f);
    float i = rintf(d * s);                    // half-to-even == jnp.round
    i = fminf(fmaxf(i, -128.0f), 127.0f);      // clip to [-2^7, 2^7 - 1]
    return i * inv;
}

// Pass 2: quantize. Scale is a scalar derived from the pass-1 max.
__global__ __launch_bounds__(256) void bq_quant_kernel(
    const float4* __restrict__ x, float4* __restrict__ out,
    const unsigned int* __restrict__ max_bits, long long n4,
    const float* __restrict__ x_scalar, float* __restrict__ out_scalar,
    long long n) {
    float max_entry = __uint_as_float(*max_bits);
    // floor(log2(max_entry)) exactly, clipped to [-128, 127]
    float me = (float)ilogbf(max_entry);
    me = fminf(fmaxf(me, -128.0f), 127.0f);
    float s   = exp2f(6.0f - me);   // 2^(-me + (bits-2)), bits=8
    float inv = exp2f(me - 6.0f);

    long long stride = (long long)gridDim.x * blockDim.x;
    for (long long i = (long long)blockIdx.x * blockDim.x + threadIdx.x;
         i < n4; i += stride) {
        float4 v = x[i];
        float4 r;
        r.x = bq_one(v.x, s, inv);
        r.y = bq_one(v.y, s, inv);
        r.z = bq_one(v.z, s, inv);
        r.w = bq_one(v.w, s, inv);
        out[i] = r;
    }
    if (blockIdx.x == 0 && threadIdx.x == 0) {
        for (long long i = n4 * 4; i < n; ++i)
            out_scalar[i] = bq_one(x_scalar[i], s, inv);
    }
}

extern "C" void kernel_launch(void* const* d_in, const int* in_sizes, int n_in,
                              void* d_out, int out_size, void* d_ws, size_t ws_size,
                              hipStream_t stream) {
    const float* x = (const float*)d_in[0];
    float* out = (float*)d_out;
    long long n = (long long)in_sizes[0];
    long long n4 = n / 4;
    unsigned int* max_bits = (unsigned int*)d_ws;

    // ws is poisoned 0xAA each call — zero it (async memset is capture-safe)
    hipMemsetAsync(max_bits, 0, sizeof(unsigned int), stream);

    const int block = 256;
    const int grid = 2048;  // 8 blocks/CU * 256 CUs; grid-stride handles rest
    bq_max_kernel<<<grid, block, 0, stream>>>(
        (const float4*)x, max_bits, n4, x, n);
    bq_quant_kernel<<<grid, block, 0, stream>>>(
        (const float4*)x, (float4*)out, max_bits, n4, x, out, n);
}

// Round 3
// 936.977 us; speedup vs baseline: 1.0184x; 1.0184x over previous
//
#include <hip/hip_runtime.h>
#include <math.h>

#define GRID 2048
#define BLOCK 256

typedef float nfloat4 __attribute__((ext_vector_type(4)));  // native vec for nt-store

// Pass 1: per-block max(|x|) partials, forward sweep (leaves tail of x hot in L3).
// Each block writes its own ws slot -> no workspace init needed (poison-safe).
__global__ __launch_bounds__(BLOCK) void bq_max_kernel(
    const float4* __restrict__ x, float* __restrict__ partials,
    long long n4, const float* __restrict__ x_scalar, long long n) {
    float m = 0.0f;
    long long stride = (long long)gridDim.x * blockDim.x;
    for (long long i = (long long)blockIdx.x * blockDim.x + threadIdx.x;
         i < n4; i += stride) {
        float4 v = x[i];
        m = fmaxf(m, fmaxf(fmaxf(fabsf(v.x), fabsf(v.y)),
                           fmaxf(fabsf(v.z), fabsf(v.w))));
    }
    // scalar tail (n not multiple of 4)
    if (blockIdx.x == 0 && threadIdx.x == 0) {
        for (long long i = n4 * 4; i < n; ++i) m = fmaxf(m, fabsf(x_scalar[i]));
    }
    // wave-64 reduce
    #pragma unroll
    for (int off = 32; off > 0; off >>= 1)
        m = fmaxf(m, __shfl_down(m, off, 64));
    __shared__ float smem[BLOCK / 64];
    int lane = threadIdx.x & 63;
    int wave = threadIdx.x >> 6;
    if (lane == 0) smem[wave] = m;
    __syncthreads();
    if (threadIdx.x == 0) {
        float bm = fmaxf(fmaxf(smem[0], smem[1]), fmaxf(smem[2], smem[3]));
        partials[blockIdx.x] = bm;   // own slot, plain store
    }
}

__device__ __forceinline__ float bq_one(float x, float s, float inv) {
    // data = where(x >= 0, max(x, 1e-10), min(x, -1e-10));  -0.0 >= 0 is true
    float d = (x >= 0.0f) ? fmaxf(x, 1e-10f) : fminf(x, -1e-10f);
    float i = rintf(d * s);                    // half-to-even == jnp.round
    i = fminf(fmaxf(i, -128.0f), 127.0f);      // clip to [-2^7, 2^7-1]
    return i * inv;
}

// Pass 2: reduce the 2048 partials in-block, then quantize sweeping in
// REVERSE order (tail of x is L3-hot from pass 1). Non-temporal stores so
// output doesn't evict x from L2/L3.
__global__ __launch_bounds__(BLOCK) void bq_quant_kernel(
    const float4* __restrict__ x, nfloat4* __restrict__ out,
    const float* __restrict__ partials, long long n4,
    const float* __restrict__ x_scalar, float* __restrict__ out_scalar,
    long long n) {
    // --- block-local reduction of the 2048 partials (8 per thread) ---
    float m = 0.0f;
    #pragma unroll
    for (int k = 0; k < GRID / BLOCK; ++k)
        m = fmaxf(m, partials[threadIdx.x + k * BLOCK]);
    #pragma unroll
    for (int off = 32; off > 0; off >>= 1)
        m = fmaxf(m, __shfl_down(m, off, 64));
    __shared__ float smem[BLOCK / 64];
    __shared__ float sc[2];
    int lane = threadIdx.x & 63;
    int wave = threadIdx.x >> 6;
    if (lane == 0) smem[wave] = m;
    __syncthreads();
    if (threadIdx.x == 0) {
        float bm = fmaxf(fmaxf(smem[0], smem[1]), fmaxf(smem[2], smem[3]));
        bm = fmaxf(bm, 1e-10f);                    // magnitude floor
        int me = ilogbf(bm);                       // floor(log2(bm)) exactly
        me = me < -128 ? -128 : (me > 127 ? 127 : me);
        sc[0] = ldexpf(1.0f, 6 - me);              // s   = 2^(-me + 6)
        sc[1] = ldexpf(1.0f, me - 6);              // inv = 2^(me - 6)
    }
    __syncthreads();
    float s = sc[0], inv = sc[1];

    // --- reverse-order grid-stride sweep ---
    long long stride = (long long)gridDim.x * blockDim.x;
    long long base = (long long)blockIdx.x * blockDim.x + threadIdx.x;
    long long iters = (n4 - base + stride - 1) / stride;   // #iters for this thread
    for (long long it = iters - 1; it >= 0; --it) {
        long long i = base + it * stride;
        float4 v = x[i];
        nfloat4 r;
        r.x = bq_one(v.x, s, inv);
        r.y = bq_one(v.y, s, inv);
        r.z = bq_one(v.z, s, inv);
        r.w = bq_one(v.w, s, inv);
        __builtin_nontemporal_store(r, &out[i]);
    }
    if (blockIdx.x == 0 && threadIdx.x == 0) {
        for (long long i = n4 * 4; i < n; ++i)
            out_scalar[i] = bq_one(x_scalar[i], s, inv);
    }
}

extern "C" void kernel_launch(void* const* d_in, const int* in_sizes, int n_in,
                              void* d_out, int out_size, void* d_ws, size_t ws_size,
                              hipStream_t stream) {
    const float* x = (const float*)d_in[0];
    float* out = (float*)d_out;
    long long n = (long long)in_sizes[0];
    long long n4 = n / 4;
    float* partials = (float*)d_ws;

    bq_max_kernel<<<GRID, BLOCK, 0, stream>>>(
        (const float4*)x, partials, n4, x, n);
    bq_quant_kernel<<<GRID, BLOCK, 0, stream>>>(
        (const float4*)x, (nfloat4*)out, partials, n4, x, out, n);
}